// Round 18
// baseline (168.886 us; speedup 1.0000x reference)
//
#include <hip/hip_runtime.h>
#include <hip/hip_bf16.h>

// SimpleMetaConvKALN: x (64,64,64,64) f32, w (32,80,3,3) f32 -> out (64,128,64,64) f32
// y = conv3x3(aug(x), w) per group; instance-norm per (b,oc); silu.
// K=64 (ones-block analytic via T[oc][ey][ex]).
// Conv: 16x64 region per block (4 tiles), 4 accs/wave share each A-read
// (1A+4B per 4 MFMAs), x halo cached in regs as PACKED BF16 (20 VGPR),
// full weight table in LDS, 4 K-phases (silu/xn/P2/P3).
// Prep: minmax || repack || T one launch; tiny reduce; bf16 y scratch.

#define NB 64
#define NH 64
#define NW 64
#define NPIX 1188      // 18 x 66 halo
#define NTASK 2376     // NPIX * 2 channel-halves

typedef __attribute__((ext_vector_type(8)))  short bf16x8;
typedef __attribute__((ext_vector_type(8)))  unsigned short u16x8;
typedef __attribute__((ext_vector_type(16))) float f32x16;

__device__ __forceinline__ float silu(float v) {
    return v / (1.0f + __expf(-v));
}
__device__ __forceinline__ unsigned short tobf(float f) {   // native cvt (RNE)
    union { __hip_bfloat16 h; unsigned short u; } cv;
    cv.h = __float2bfloat16(f);
    return cv.u;
}
__device__ __forceinline__ float frombf(short u) {
    return __uint_as_float(((unsigned)(unsigned short)u) << 16);
}

// blk 0-4095: per-plane min/max ; blk 4096-4167: repack w ; blk 4168: T table
__global__ __launch_bounds__(256) void prep_kernel(const float* __restrict__ x,
                                                   const float* __restrict__ w,
                                                   float* __restrict__ pmm,
                                                   unsigned short* __restrict__ wpk,
                                                   float* __restrict__ Tt) {
    int blk = blockIdx.x;
    int t = threadIdx.x;
    if (blk < 4096) {
        int plane = blk;          // b*64 + ch
        const float4* p = (const float4*)(x + (size_t)plane * 4096);
        float mn = 3.4e38f, mx = -3.4e38f;
        #pragma unroll
        for (int k = 0; k < 4; ++k) {
            float4 v = p[t + k * 256];
            mn = fminf(mn, fminf(fminf(v.x, v.y), fminf(v.z, v.w)));
            mx = fmaxf(mx, fmaxf(fmaxf(v.x, v.y), fmaxf(v.z, v.w)));
        }
        #pragma unroll
        for (int off = 32; off; off >>= 1) {
            mn = fminf(mn, __shfl_xor(mn, off));
            mx = fmaxf(mx, __shfl_xor(mx, off));
        }
        __shared__ float smn[4], smx[4];
        int wid = t >> 6, lane = t & 63;
        if (lane == 0) { smn[wid] = mn; smx[wid] = mx; }
        __syncthreads();
        if (t == 0) {
            mn = fminf(fminf(smn[0], smn[1]), fminf(smn[2], smn[3]));
            mx = fmaxf(fmaxf(smx[0], smx[1]), fmaxf(smx[2], smx[3]));
            pmm[plane * 2]     = mn;
            pmm[plane * 2 + 1] = mx;
        }
    } else if (blk < 4168) {
        int idx = (blk - 4096) * 256 + t;    // < 18432 = 4*9*2*32*8
        int p   = idx / 4608;                // phase
        int r1  = idx - p * 4608;
        int tap = r1 / 512;
        int r2  = r1 - tap * 512;
        int h   = r2 >> 8;                   // k-half within phase
        int oc  = (r2 >> 3) & 31;
        int j   = r2 & 7;
        int k   = p * 16 + h * 8 + j;
        int orig = (k < 16) ? k : (k + 16);  // skip ones block (orig 16..31)
        wpk[idx] = tobf(w[oc * 720 + orig * 9 + tap]);
    } else {
        for (int i = t; i < 288; i += 256) {
            int oc = i / 9, ty = i - oc * 9;
            int ey = ty / 3, ex = ty - ey * 3;
            int ky0 = (ey == 0) ? 1 : 0, ky1 = (ey == 2) ? 1 : 2;
            int kx0 = (ex == 0) ? 1 : 0, kx1 = (ex == 2) ? 1 : 2;
            float s = 0.f;
            for (int c = 0; c < 16; ++c)
                for (int ky = ky0; ky <= ky1; ++ky)
                    for (int kx = kx0; kx <= kx1; ++kx)
                        s += w[oc * 720 + (16 + c) * 9 + ky * 3 + kx];
            Tt[i] = s;
        }
    }
}

// 4 blocks: reduce pmm -> wsf[g]
__global__ __launch_bounds__(256) void reduce_kernel(const float* __restrict__ pmm,
                                                     float* __restrict__ wsf) {
    int g = blockIdx.x;
    int t = threadIdx.x;
    float mn = 3.4e38f, mx = -3.4e38f;
    #pragma unroll
    for (int j = 0; j < 4; ++j) {
        int p = t + j * 256;             // 0..1023
        int b = p >> 4, c = p & 15;
        int plane = b * 64 + g * 16 + c;
        mn = fminf(mn, pmm[plane * 2]);
        mx = fmaxf(mx, pmm[plane * 2 + 1]);
    }
    #pragma unroll
    for (int off = 32; off; off >>= 1) {
        mn = fminf(mn, __shfl_xor(mn, off));
        mx = fmaxf(mx, __shfl_xor(mx, off));
    }
    __shared__ float smn[4], smx[4];
    int wid = t >> 6, lane = t & 63;
    if (lane == 0) { smn[wid] = mn; smx[wid] = mx; }
    __syncthreads();
    if (t == 0) {
        mn = fminf(fminf(smn[0], smn[1]), fminf(smn[2], smn[3]));
        mx = fmaxf(fmaxf(smx[0], smx[1]), fmaxf(smx[2], smx[3]));
        wsf[g * 2]     = mn;
        wsf[g * 2 + 1] = mx;
    }
}

__global__ __launch_bounds__(512, 4) void conv_mfma_kernel(const float* __restrict__ x,
                                                           const float* __restrict__ wsf,
                                                           const unsigned short* __restrict__ wpk,
                                                           const float* __restrict__ Tt,
                                                           float* __restrict__ out,
                                                           unsigned short* __restrict__ yscr) {
    __shared__ unsigned short wl[18432];       // [p][tap][h][oc][8]  36864 B
    __shared__ unsigned short augp[NPIX * 16]; // [h][pix 0..1187][8] 38016 B
    __shared__ float Tl[288];                  // 1152 B

    // XCD swizzle over 1024 blocks
    int flat = blockIdx.x;                       // 0..1023
    int f = ((flat & 7) << 7) | (flat >> 3);     // bijective
    int q = f & 3;                               // row band: 16 rows x 64 cols
    int bg = f >> 2;
    int b = bg & 63;
    int g = bg >> 6;
    int th0 = q * 16;

    float xmin = wsf[g * 2];
    float xmax = wsf[g * 2 + 1];
    float inv = 2.0f / (xmax - xmin);

    const float* xg = x + ((size_t)b * 64 + g * 16) * 4096;
    int t = threadIdx.x;

    // ---- full weight table: global -> LDS once (2304 uint4) ----
    {
        const uint4* srcw = (const uint4*)wpk;
        uint4* dstw = (uint4*)wl;
        #pragma unroll
        for (int i = 0; i < 5; ++i) {
            int idx = t + i * 512;
            if (idx < 2304) dstw[idx] = srcw[idx];
        }
    }
    if (t < 288) Tl[t] = Tt[t];

    // ---- x halo region -> registers as PACKED BF16 (5 slots x 8ch) ----
    bf16x8 rv[5];
    #pragma unroll
    for (int i = 0; i < 5; ++i) {
        int idx = t + i * 512;
        if (idx < NTASK) {
            int half = idx >= NPIX ? 1 : 0;
            int pix = idx - half * NPIX;
            int ly = pix / 66, lx = pix - ly * 66;
            int gh = th0 + ly - 1, gw = lx - 1;
            bool ok = (gh >= 0 && gh < NH && gw >= 0 && gw < NW);
            const float* s = xg + (size_t)(half * 8) * 4096 + gh * 64 + gw;
            bf16x8 v;
            #pragma unroll
            for (int j = 0; j < 8; ++j)
                v[j] = (short)tobf(ok ? s[(size_t)j * 4096] : 0.f);
            rv[i] = v;
        }
    }

    int wv = t >> 6;
    int lane = t & 63;
    int lo = lane & 31, hi = lane >> 5;
    int py = 2 * wv + (lo >> 4), px = lo & 15;

    f32x16 acc0 = {}, acc1 = {}, acc2 = {}, acc3 = {};

    // ---- 4 K-phases: 0=silu, 1=xn, 2=P2, 3=P3 ----
    #pragma unroll
    for (int p = 0; p < 4; ++p) {
        // stage this phase's transform from the bf16 reg-cache
        #pragma unroll
        for (int i = 0; i < 5; ++i) {
            int idx = t + i * 512;
            if (idx < NTASK) {
                int half = idx >= NPIX ? 1 : 0;
                int pix = idx - half * NPIX;
                int ly = pix / 66, lx = pix - ly * 66;
                int gh = th0 + ly - 1, gw = lx - 1;
                bool ok = (gh >= 0 && gh < NH && gw >= 0 && gw < NW);
                bf16x8 vv = rv[i];
                bf16x8 o;
                #pragma unroll
                for (int j = 0; j < 8; ++j) {
                    float val = frombf(vv[j]);
                    float r;
                    if (p == 0) {
                        r = silu(val);               // silu(0)=0: OOB safe
                    } else {
                        float xn = (val - xmin) * inv - 1.f;
                        if (p == 1) r = xn;
                        else {
                            float x2 = xn * xn;
                            r = (p == 2) ? (1.5f * x2 - 0.5f)
                                         : ((2.5f * x2 - 1.5f) * xn);
                        }
                        r = ok ? r : 0.f;
                    }
                    o[j] = (short)tobf(r);
                }
                *(bf16x8*)&augp[(half * NPIX + pix) * 8] = o;
            }
        }
        __syncthreads();

        // 9 taps: 1 A-read + 4 B-reads -> 4 MFMAs (independent acc chains)
        #pragma unroll
        for (int tap = 0; tap < 9; ++tap) {
            const int ky = tap / 3, kx = tap % 3;
            const int hp = (py + ky) * 66 + (px + kx);
            bf16x8 Af = *(const bf16x8*)&wl[(((p * 9 + tap) * 2 + hi) * 32 + lo) * 8];
            bf16x8 B0 = *(const bf16x8*)&augp[(hi * NPIX + hp) * 8];
            bf16x8 B1 = *(const bf16x8*)&augp[(hi * NPIX + hp + 16) * 8];
            bf16x8 B2 = *(const bf16x8*)&augp[(hi * NPIX + hp + 32) * 8];
            bf16x8 B3 = *(const bf16x8*)&augp[(hi * NPIX + hp + 48) * 8];
            acc0 = __builtin_amdgcn_mfma_f32_32x32x16_bf16(Af, B0, acc0, 0, 0, 0);
            acc1 = __builtin_amdgcn_mfma_f32_32x32x16_bf16(Af, B1, acc1, 0, 0, 0);
            acc2 = __builtin_amdgcn_mfma_f32_32x32x16_bf16(Af, B2, acc2, 0, 0, 0);
            acc3 = __builtin_amdgcn_mfma_f32_32x32x16_bf16(Af, B3, acc3, 0, 0, 0);
        }
        __syncthreads();
    }

    // ---- epilogue: ones-term + stores (bf16 scratch if available) ----
    int h = th0 + py;
    int ey = (h == 0) ? 0 : ((h == NH - 1) ? 2 : 1);
    size_t gbase = ((size_t)b * 128 + g * 32) * 4096 + (size_t)h * 64;

    int wc0 = px,      et0 = ey * 3 + ((wc0 == 0) ? 0 : 1);
    int wc1 = 16 + px, et1 = ey * 3 + 1;
    int wc2 = 32 + px, et2 = ey * 3 + 1;
    int wc3 = 48 + px, et3 = ey * 3 + ((wc3 == NW - 1) ? 2 : 1);

    if (yscr) {
        #pragma unroll
        for (int rr = 0; rr < 16; ++rr) {
            int oc = (rr & 3) + 8 * (rr >> 2) + 4 * hi;
            size_t o = gbase + (size_t)oc * 4096;
            yscr[o + wc0] = tobf(acc0[rr] + Tl[oc * 9 + et0]);
            yscr[o + wc1] = tobf(acc1[rr] + Tl[oc * 9 + et1]);
            yscr[o + wc2] = tobf(acc2[rr] + Tl[oc * 9 + et2]);
            yscr[o + wc3] = tobf(acc3[rr] + Tl[oc * 9 + et3]);
        }
    } else {
        #pragma unroll
        for (int rr = 0; rr < 16; ++rr) {
            int oc = (rr & 3) + 8 * (rr >> 2) + 4 * hi;
            size_t o = gbase + (size_t)oc * 4096;
            out[o + wc0] = acc0[rr] + Tl[oc * 9 + et0];
            out[o + wc1] = acc1[rr] + Tl[oc * 9 + et1];
            out[o + wc2] = acc2[rr] + Tl[oc * 9 + et2];
            out[o + wc3] = acc3[rr] + Tl[oc * 9 + et3];
        }
    }
}

// ---- norm from bf16 scratch: read 67MB, write 134MB ----
__global__ __launch_bounds__(256) void norm_bf16_kernel(const unsigned short* __restrict__ yscr,
                                                        float* __restrict__ out) {
    int plane = blockIdx.x;      // b*128 + ch
    const u16x8* p = (const u16x8*)(yscr + (size_t)plane * 4096);
    int t = threadIdx.x;
    float v[2][8];
    float s = 0.f, s2 = 0.f;
    #pragma unroll
    for (int k = 0; k < 2; ++k) {
        u16x8 u = p[t + k * 256];
        #pragma unroll
        for (int j = 0; j < 8; ++j) {
            float f = __uint_as_float((unsigned)u[j] << 16);
            v[k][j] = f;
            s += f;
            s2 += f * f;
        }
    }
    #pragma unroll
    for (int off = 32; off; off >>= 1) {
        s  += __shfl_xor(s, off);
        s2 += __shfl_xor(s2, off);
    }
    __shared__ float ss[4], ss2[4];
    int wid = t >> 6, lane = t & 63;
    if (lane == 0) { ss[wid] = s; ss2[wid] = s2; }
    __syncthreads();
    s  = ss[0] + ss[1] + ss[2] + ss[3];
    s2 = ss2[0] + ss2[1] + ss2[2] + ss2[3];
    float mean = s * (1.f / 4096.f);
    float var  = fmaxf(s2 * (1.f / 4096.f) - mean * mean, 0.f);
    float istd = rsqrtf(var + 1e-5f);
    float4* o = (float4*)(out + (size_t)plane * 4096);
    #pragma unroll
    for (int k = 0; k < 2; ++k) {
        float4 a, bq;
        a.x = silu((v[k][0] - mean) * istd);
        a.y = silu((v[k][1] - mean) * istd);
        a.z = silu((v[k][2] - mean) * istd);
        a.w = silu((v[k][3] - mean) * istd);
        bq.x = silu((v[k][4] - mean) * istd);
        bq.y = silu((v[k][5] - mean) * istd);
        bq.z = silu((v[k][6] - mean) * istd);
        bq.w = silu((v[k][7] - mean) * istd);
        o[(t + k * 256) * 2]     = a;
        o[(t + k * 256) * 2 + 1] = bq;
    }
}

// ---- fallback: in-place f32 norm ----
__global__ __launch_bounds__(256) void norm_kernel(float* __restrict__ out) {
    int plane = blockIdx.x;      // b*128 + ch
    float4* p = (float4*)(out + (size_t)plane * 4096);
    int t = threadIdx.x;
    float4 v[4];
    float s = 0.f, s2 = 0.f;
    #pragma unroll
    for (int k = 0; k < 4; ++k) {
        v[k] = p[t + k * 256];
        s  += v[k].x + v[k].y + v[k].z + v[k].w;
        s2 += v[k].x * v[k].x + v[k].y * v[k].y + v[k].z * v[k].z + v[k].w * v[k].w;
    }
    #pragma unroll
    for (int off = 32; off; off >>= 1) {
        s  += __shfl_xor(s, off);
        s2 += __shfl_xor(s2, off);
    }
    __shared__ float ss[4], ss2[4];
    int wid = t >> 6, lane = t & 63;
    if (lane == 0) { ss[wid] = s; ss2[wid] = s2; }
    __syncthreads();
    s  = ss[0] + ss[1] + ss[2] + ss[3];
    s2 = ss2[0] + ss2[1] + ss2[2] + ss2[3];
    float mean = s * (1.f / 4096.f);
    float var  = fmaxf(s2 * (1.f / 4096.f) - mean * mean, 0.f);
    float istd = rsqrtf(var + 1e-5f);
    #pragma unroll
    for (int k = 0; k < 4; ++k) {
        float4 o;
        o.x = (v[k].x - mean) * istd; o.x = silu(o.x);
        o.y = (v[k].y - mean) * istd; o.y = silu(o.y);
        o.z = (v[k].z - mean) * istd; o.z = silu(o.z);
        o.w = (v[k].w - mean) * istd; o.w = silu(o.w);
        p[t + k * 256] = o;
    }
}

extern "C" void kernel_launch(void* const* d_in, const int* in_sizes, int n_in,
                              void* d_out, int out_size, void* d_ws, size_t ws_size,
                              hipStream_t stream) {
    const float* x = (const float*)d_in[0];
    const float* w = (const float*)d_in[1];
    float* out = (float*)d_out;
    float* wsf = (float*)d_ws;                                        // 8 floats
    float* pmm = (float*)((char*)d_ws + 64);                          // 8192 floats
    unsigned short* wpk = (unsigned short*)((char*)d_ws + 64 + 32768);// 18432 bf16
    float* Tt = (float*)((char*)d_ws + 64 + 32768 + 36864);           // 288 floats

    const size_t YSCR_OFF = 131072;
    const size_t YSCR_BYTES = (size_t)64 * 128 * 4096 * 2;            // 67.1 MB
    unsigned short* yscr = (ws_size >= YSCR_OFF + YSCR_BYTES)
                         ? (unsigned short*)((char*)d_ws + YSCR_OFF) : nullptr;

    hipLaunchKernelGGL(prep_kernel, dim3(4169), dim3(256), 0, stream, x, w, pmm, wpk, Tt);
    hipLaunchKernelGGL(reduce_kernel, dim3(4), dim3(256), 0, stream, pmm, wsf);
    hipLaunchKernelGGL(conv_mfma_kernel, dim3(1024), dim3(512), 0, stream, x, wsf, wpk, Tt, out, yscr);
    if (yscr)
        hipLaunchKernelGGL(norm_bf16_kernel, dim3(NB * 128), dim3(256), 0, stream, yscr, out);
    else
        hipLaunchKernelGGL(norm_kernel, dim3(NB * 128), dim3(256), 0, stream, out);
}

// Round 19
// 127.905 us; speedup vs baseline: 1.3204x; 1.3204x over previous
//
#include <hip/hip_runtime.h>
#include <hip/hip_bf16.h>

// SimpleMetaConvKALN: x (64,64,64,64) f32, w (32,80,3,3) f32 -> out (64,128,64,64) f32
// y = conv3x3(aug(x), w) per group; instance-norm per (b,oc); silu.
// K=64 (ones-block analytic via T[oc][ey][ex]).
// Conv (R16 best): 16x32 region per block (2 tiles), 2 accs/wave share each
// A-read (1A+2B per 2 MFMAs), f32 halo cache r[3][8], full weight table in
// LDS, 4 K-phases (silu/xn/P2/P3), grid 2048 + XCD swizzle.
// Prep: minmax || repack || T one launch; tiny reduce; bf16 y scratch.

#define NB 64
#define NH 64
#define NW 64

typedef __attribute__((ext_vector_type(8)))  short bf16x8;
typedef __attribute__((ext_vector_type(8)))  unsigned short u16x8;
typedef __attribute__((ext_vector_type(16))) float f32x16;

__device__ __forceinline__ float silu(float v) {
    return v / (1.0f + __expf(-v));
}
__device__ __forceinline__ unsigned short tobf(float f) {   // native cvt (RNE)
    union { __hip_bfloat16 h; unsigned short u; } cv;
    cv.h = __float2bfloat16(f);
    return cv.u;
}

// blk 0-4095: per-plane min/max ; blk 4096-4167: repack w ; blk 4168: T table
__global__ __launch_bounds__(256) void prep_kernel(const float* __restrict__ x,
                                                   const float* __restrict__ w,
                                                   float* __restrict__ pmm,
                                                   unsigned short* __restrict__ wpk,
                                                   float* __restrict__ Tt) {
    int blk = blockIdx.x;
    int t = threadIdx.x;
    if (blk < 4096) {
        int plane = blk;          // b*64 + ch
        const float4* p = (const float4*)(x + (size_t)plane * 4096);
        float mn = 3.4e38f, mx = -3.4e38f;
        #pragma unroll
        for (int k = 0; k < 4; ++k) {
            float4 v = p[t + k * 256];
            mn = fminf(mn, fminf(fminf(v.x, v.y), fminf(v.z, v.w)));
            mx = fmaxf(mx, fmaxf(fmaxf(v.x, v.y), fmaxf(v.z, v.w)));
        }
        #pragma unroll
        for (int off = 32; off; off >>= 1) {
            mn = fminf(mn, __shfl_xor(mn, off));
            mx = fmaxf(mx, __shfl_xor(mx, off));
        }
        __shared__ float smn[4], smx[4];
        int wid = t >> 6, lane = t & 63;
        if (lane == 0) { smn[wid] = mn; smx[wid] = mx; }
        __syncthreads();
        if (t == 0) {
            mn = fminf(fminf(smn[0], smn[1]), fminf(smn[2], smn[3]));
            mx = fmaxf(fmaxf(smx[0], smx[1]), fmaxf(smx[2], smx[3]));
            pmm[plane * 2]     = mn;
            pmm[plane * 2 + 1] = mx;
        }
    } else if (blk < 4168) {
        int idx = (blk - 4096) * 256 + t;    // < 18432 = 4*9*2*32*8
        int p   = idx / 4608;                // phase
        int r1  = idx - p * 4608;
        int tap = r1 / 512;
        int r2  = r1 - tap * 512;
        int h   = r2 >> 8;                   // k-half within phase
        int oc  = (r2 >> 3) & 31;
        int j   = r2 & 7;
        int k   = p * 16 + h * 8 + j;
        int orig = (k < 16) ? k : (k + 16);  // skip ones block (orig 16..31)
        wpk[idx] = tobf(w[oc * 720 + orig * 9 + tap]);
    } else {
        for (int i = t; i < 288; i += 256) {
            int oc = i / 9, ty = i - oc * 9;
            int ey = ty / 3, ex = ty - ey * 3;
            int ky0 = (ey == 0) ? 1 : 0, ky1 = (ey == 2) ? 1 : 2;
            int kx0 = (ex == 0) ? 1 : 0, kx1 = (ex == 2) ? 1 : 2;
            float s = 0.f;
            for (int c = 0; c < 16; ++c)
                for (int ky = ky0; ky <= ky1; ++ky)
                    for (int kx = kx0; kx <= kx1; ++kx)
                        s += w[oc * 720 + (16 + c) * 9 + ky * 3 + kx];
            Tt[i] = s;
        }
    }
}

// 4 blocks: reduce pmm -> wsf[g]
__global__ __launch_bounds__(256) void reduce_kernel(const float* __restrict__ pmm,
                                                     float* __restrict__ wsf) {
    int g = blockIdx.x;
    int t = threadIdx.x;
    float mn = 3.4e38f, mx = -3.4e38f;
    #pragma unroll
    for (int j = 0; j < 4; ++j) {
        int p = t + j * 256;             // 0..1023
        int b = p >> 4, c = p & 15;
        int plane = b * 64 + g * 16 + c;
        mn = fminf(mn, pmm[plane * 2]);
        mx = fmaxf(mx, pmm[plane * 2 + 1]);
    }
    #pragma unroll
    for (int off = 32; off; off >>= 1) {
        mn = fminf(mn, __shfl_xor(mn, off));
        mx = fmaxf(mx, __shfl_xor(mx, off));
    }
    __shared__ float smn[4], smx[4];
    int wid = t >> 6, lane = t & 63;
    if (lane == 0) { smn[wid] = mn; smx[wid] = mx; }
    __syncthreads();
    if (t == 0) {
        mn = fminf(fminf(smn[0], smn[1]), fminf(smn[2], smn[3]));
        mx = fmaxf(fmaxf(smx[0], smx[1]), fmaxf(smx[2], smx[3]));
        wsf[g * 2]     = mn;
        wsf[g * 2 + 1] = mx;
    }
}

__global__ __launch_bounds__(512, 4) void conv_mfma_kernel(const float* __restrict__ x,
                                                           const float* __restrict__ wsf,
                                                           const unsigned short* __restrict__ wpk,
                                                           const float* __restrict__ Tt,
                                                           float* __restrict__ out,
                                                           unsigned short* __restrict__ yscr) {
    __shared__ unsigned short wl[18432];    // [p][tap][h][oc][8]  36864 B
    __shared__ unsigned short augp[9792];   // [h][pix 0..611][8]  19584 B (18x34 halo)
    __shared__ float Tl[288];               // 1152 B

    // XCD swizzle over 2048 blocks
    int flat = blockIdx.x;                       // 0..2047
    int f = ((flat & 7) << 8) | (flat >> 3);     // bijective
    int q = f & 7;                               // region: 4x2 of 16x32
    int bg = f >> 3;
    int b = bg & 63;
    int g = bg >> 6;
    int th0 = (q >> 1) * 16, tw0 = (q & 1) * 32;

    float xmin = wsf[g * 2];
    float xmax = wsf[g * 2 + 1];
    float inv = 2.0f / (xmax - xmin);

    const float* xg = x + ((size_t)b * 64 + g * 16) * 4096;
    int t = threadIdx.x;

    // ---- full weight table: global -> LDS once (2304 uint4) ----
    {
        const uint4* srcw = (const uint4*)wpk;
        uint4* dstw = (uint4*)wl;
        #pragma unroll
        for (int i = 0; i < 5; ++i) {
            int idx = t + i * 512;
            if (idx < 2304) dstw[idx] = srcw[idx];
        }
    }
    if (t < 288) Tl[t] = Tt[t];

    // ---- x halo region into registers: 1224 tasks = 612 px x 2 ch-halves ----
    float r[3][8];
    bool okv[3];
    #pragma unroll
    for (int i = 0; i < 3; ++i) {
        okv[i] = false;
        int idx = t + i * 512;
        if (idx < 1224) {
            int half = idx >= 612 ? 1 : 0;
            int pix = idx - half * 612;
            int ly = pix / 34, lx = pix - ly * 34;
            int gh = th0 + ly - 1, gw = tw0 + lx - 1;
            bool ok = (gh >= 0 && gh < NH && gw >= 0 && gw < NW);
            okv[i] = ok;
            const float* s = xg + (size_t)(half * 8) * 4096 + gh * 64 + gw;
            #pragma unroll
            for (int j = 0; j < 8; ++j)
                r[i][j] = ok ? s[(size_t)j * 4096] : 0.f;
        }
    }

    int wv = t >> 6;
    int lane = t & 63;
    int lo = lane & 31, hi = lane >> 5;
    int py = 2 * wv + (lo >> 4), px = lo & 15;

    f32x16 acc0 = {}, acc1 = {};   // left (cols px), right (cols px+16)

    // ---- 4 K-phases: 0=silu, 1=xn, 2=P2, 3=P3 ----
    #pragma unroll
    for (int p = 0; p < 4; ++p) {
        // stage this phase's transform (all b128 writes, reg->VALU->LDS)
        #pragma unroll
        for (int i = 0; i < 3; ++i) {
            int idx = t + i * 512;
            if (idx < 1224) {
                int half = idx >= 612 ? 1 : 0;
                int pix = idx - half * 612;
                bf16x8 v;
                #pragma unroll
                for (int j = 0; j < 8; ++j) {
                    float val = r[i][j];
                    float o;
                    if (p == 0) {
                        o = silu(val);               // silu(0)=0: OOB safe
                    } else {
                        float xn = (val - xmin) * inv - 1.f;
                        if (p == 1) o = xn;
                        else {
                            float x2 = xn * xn;
                            o = (p == 2) ? (1.5f * x2 - 0.5f)
                                         : ((2.5f * x2 - 1.5f) * xn);
                        }
                        o = okv[i] ? o : 0.f;
                    }
                    v[j] = (short)tobf(o);
                }
                *(bf16x8*)&augp[(half * 612 + pix) * 8] = v;
            }
        }
        __syncthreads();

        // 9 taps: 1 A-read + 2 B-reads -> 2 MFMAs (independent acc chains)
        #pragma unroll
        for (int tap = 0; tap < 9; ++tap) {
            const int ky = tap / 3, kx = tap % 3;
            const int hp = (py + ky) * 34 + (px + kx);
            bf16x8 Af = *(const bf16x8*)&wl[(((p * 9 + tap) * 2 + hi) * 32 + lo) * 8];
            bf16x8 Bf0 = *(const bf16x8*)&augp[(hi * 612 + hp) * 8];
            bf16x8 Bf1 = *(const bf16x8*)&augp[(hi * 612 + hp + 16) * 8];
            acc0 = __builtin_amdgcn_mfma_f32_32x32x16_bf16(Af, Bf0, acc0, 0, 0, 0);
            acc1 = __builtin_amdgcn_mfma_f32_32x32x16_bf16(Af, Bf1, acc1, 0, 0, 0);
        }
        __syncthreads();
    }

    // ---- epilogue: ones-term + stores (bf16 scratch if available) ----
    int h = th0 + py;
    int ey = (h == 0) ? 0 : ((h == NH - 1) ? 2 : 1);
    size_t gbase = ((size_t)b * 128 + g * 32) * 4096 + (size_t)h * 64;

    int wc0 = tw0 + px;
    int ex0 = (wc0 == 0) ? 0 : ((wc0 == NW - 1) ? 2 : 1);
    int et0 = ey * 3 + ex0;
    int wc1 = tw0 + 16 + px;
    int ex1 = (wc1 == 0) ? 0 : ((wc1 == NW - 1) ? 2 : 1);
    int et1 = ey * 3 + ex1;

    if (yscr) {
        #pragma unroll
        for (int rr = 0; rr < 16; ++rr) {
            int oc = (rr & 3) + 8 * (rr >> 2) + 4 * hi;
            size_t o = gbase + (size_t)oc * 4096;
            yscr[o + wc0] = tobf(acc0[rr] + Tl[oc * 9 + et0]);
            yscr[o + wc1] = tobf(acc1[rr] + Tl[oc * 9 + et1]);
        }
    } else {
        #pragma unroll
        for (int rr = 0; rr < 16; ++rr) {
            int oc = (rr & 3) + 8 * (rr >> 2) + 4 * hi;
            size_t o = gbase + (size_t)oc * 4096;
            out[o + wc0] = acc0[rr] + Tl[oc * 9 + et0];
            out[o + wc1] = acc1[rr] + Tl[oc * 9 + et1];
        }
    }
}

// ---- norm from bf16 scratch: read 67MB, write 134MB ----
__global__ __launch_bounds__(256) void norm_bf16_kernel(const unsigned short* __restrict__ yscr,
                                                        float* __restrict__ out) {
    int plane = blockIdx.x;      // b*128 + ch
    const u16x8* p = (const u16x8*)(yscr + (size_t)plane * 4096);
    int t = threadIdx.x;
    float v[2][8];
    float s = 0.f, s2 = 0.f;
    #pragma unroll
    for (int k = 0; k < 2; ++k) {
        u16x8 u = p[t + k * 256];
        #pragma unroll
        for (int j = 0; j < 8; ++j) {
            float f = __uint_as_float((unsigned)u[j] << 16);
            v[k][j] = f;
            s += f;
            s2 += f * f;
        }
    }
    #pragma unroll
    for (int off = 32; off; off >>= 1) {
        s  += __shfl_xor(s, off);
        s2 += __shfl_xor(s2, off);
    }
    __shared__ float ss[4], ss2[4];
    int wid = t >> 6, lane = t & 63;
    if (lane == 0) { ss[wid] = s; ss2[wid] = s2; }
    __syncthreads();
    s  = ss[0] + ss[1] + ss[2] + ss[3];
    s2 = ss2[0] + ss2[1] + ss2[2] + ss2[3];
    float mean = s * (1.f / 4096.f);
    float var  = fmaxf(s2 * (1.f / 4096.f) - mean * mean, 0.f);
    float istd = rsqrtf(var + 1e-5f);
    float4* o = (float4*)(out + (size_t)plane * 4096);
    #pragma unroll
    for (int k = 0; k < 2; ++k) {
        float4 a, bq;
        a.x = silu((v[k][0] - mean) * istd);
        a.y = silu((v[k][1] - mean) * istd);
        a.z = silu((v[k][2] - mean) * istd);
        a.w = silu((v[k][3] - mean) * istd);
        bq.x = silu((v[k][4] - mean) * istd);
        bq.y = silu((v[k][5] - mean) * istd);
        bq.z = silu((v[k][6] - mean) * istd);
        bq.w = silu((v[k][7] - mean) * istd);
        o[(t + k * 256) * 2]     = a;
        o[(t + k * 256) * 2 + 1] = bq;
    }
}

// ---- fallback: in-place f32 norm ----
__global__ __launch_bounds__(256) void norm_kernel(float* __restrict__ out) {
    int plane = blockIdx.x;      // b*128 + ch
    float4* p = (float4*)(out + (size_t)plane * 4096);
    int t = threadIdx.x;
    float4 v[4];
    float s = 0.f, s2 = 0.f;
    #pragma unroll
    for (int k = 0; k < 4; ++k) {
        v[k] = p[t + k * 256];
        s  += v[k].x + v[k].y + v[k].z + v[k].w;
        s2 += v[k].x * v[k].x + v[k].y * v[k].y + v[k].z * v[k].z + v[k].w * v[k].w;
    }
    #pragma unroll
    for (int off = 32; off; off >>= 1) {
        s  += __shfl_xor(s, off);
        s2 += __shfl_xor(s2, off);
    }
    __shared__ float ss[4], ss2[4];
    int wid = t >> 6, lane = t & 63;
    if (lane == 0) { ss[wid] = s; ss2[wid] = s2; }
    __syncthreads();
    s  = ss[0] + ss[1] + ss[2] + ss[3];
    s2 = ss2[0] + ss2[1] + ss2[2] + ss2[3];
    float mean = s * (1.f / 4096.f);
    float var  = fmaxf(s2 * (1.f / 4096.f) - mean * mean, 0.f);
    float istd = rsqrtf(var + 1e-5f);
    #pragma unroll
    for (int k = 0; k < 4; ++k) {
        float4 o;
        o.x = (v[k].x - mean) * istd; o.x = silu(o.x);
        o.y = (v[k].y - mean) * istd; o.y = silu(o.y);
        o.z = (v[k].z - mean) * istd; o.z = silu(o.z);
        o.w = (v[k].w - mean) * istd; o.w = silu(o.w);
        p[t + k * 256] = o;
    }
}

extern "C" void kernel_launch(void* const* d_in, const int* in_sizes, int n_in,
                              void* d_out, int out_size, void* d_ws, size_t ws_size,
                              hipStream_t stream) {
    const float* x = (const float*)d_in[0];
    const float* w = (const float*)d_in[1];
    float* out = (float*)d_out;
    float* wsf = (float*)d_ws;                                        // 8 floats
    float* pmm = (float*)((char*)d_ws + 64);                          // 8192 floats
    unsigned short* wpk = (unsigned short*)((char*)d_ws + 64 + 32768);// 18432 bf16
    float* Tt = (float*)((char*)d_ws + 64 + 32768 + 36864);           // 288 floats

    const size_t YSCR_OFF = 131072;
    const size_t YSCR_BYTES = (size_t)64 * 128 * 4096 * 2;            // 67.1 MB
    unsigned short* yscr = (ws_size >= YSCR_OFF + YSCR_BYTES)
                         ? (unsigned short*)((char*)d_ws + YSCR_OFF) : nullptr;

    hipLaunchKernelGGL(prep_kernel, dim3(4169), dim3(256), 0, stream, x, w, pmm, wpk, Tt);
    hipLaunchKernelGGL(reduce_kernel, dim3(4), dim3(256), 0, stream, pmm, wsf);
    hipLaunchKernelGGL(conv_mfma_kernel, dim3(2048), dim3(512), 0, stream, x, wsf, wpk, Tt, out, yscr);
    if (yscr)
        hipLaunchKernelGGL(norm_bf16_kernel, dim3(NB * 128), dim3(256), 0, stream, yscr, out);
    else
        hipLaunchKernelGGL(norm_kernel, dim3(NB * 128), dim3(256), 0, stream, out);
}